// Round 1
// baseline (67.443 us; speedup 1.0000x reference)
//
#include <hip/hip_runtime.h>

// out[b,i] = relu( max_{j=1..64}( hf_pad[b,i+j] - j ) - hf[b,i] )
// With chunk-local g[k] = hf[base+k] - k (base shift cancels in differences):
//   out[i] = relu( max_{k=i+1..i+64} g[k] - g[i] )
//
// Register-transposed Gil-Werman, v2 ("next8-local"): each lane owns 8
// consecutive elements x[0..7] (chunk of 512 per wave) AND loads the 8
// elements 64 positions ahead (y[0..7] = lane L+8's x, or the halo for
// lanes 56-63; ~87% L1-hit, +256B/wave HBM like the old halo read).
// Window (i, i+64] at lane L pos t =
//     own suffix suf[t+1..7]
//   ∪ middle: lo lanes: m[L+1..L+7]  (clamped doubling, 4 shuffles)
//             hi lanes: m[L+1..63] (same doubling tail) ∪ m2[56..L-1]
//                       (8-lane-group exclusive scan of next8 aggregates,
//                        4 shuffles)
//   ∪ own pre2[t]  (prefix of next8 — LOCAL register, no shuffle)
// 8 wave64 shuffles per 512 outputs (was 26, incl. 8 ds_bpermute + a
// 6-deep dependent halo scan). Chunk-local k offsets cut cancellation
// (|g| <= ~580 instead of ~4100).

#define N_COLS 4096
#define CHUNK 512
#define NEG_INF (-3.0e38f)
#define PAD_VAL (-1000.0f)

typedef float vfloat4 __attribute__((ext_vector_type(4)));

__global__ __launch_bounds__(256, 8) void slide_max_kernel(
    const float* __restrict__ hf, float* __restrict__ out) {
  const int lane = threadIdx.x & 63;
  const int wid = (blockIdx.x << 2) | (threadIdx.x >> 6);  // global wave id
  const int row = wid >> 3;                                // 8 chunks per row
  const int chunk = wid & 7;
  const int base = chunk * CHUNK;

  const float* rowp = hf + (size_t)row * N_COLS;
  float* outp = out + (size_t)row * N_COLS;

  // ---- primary: 8 consecutive floats per lane (two dwordx4) ----
  const vfloat4* rp4 = (const vfloat4*)(rowp + base);
  vfloat4 v0 = rp4[2 * lane];
  vfloat4 v1 = rp4[2 * lane + 1];

  // ---- next8: elements base + 8*lane + 64 .. +71 (lane L+8's primary,
  //      or halo for lanes 56-63). OOB only for chunk 7, lanes >= 56. ----
  const int nb = base + 8 * lane + 64;
  vfloat4 u0, u1;
  if (nb < N_COLS) {
    u0 = rp4[2 * lane + 16];
    u1 = rp4[2 * lane + 17];
  } else {
    u0 = vfloat4{PAD_VAL, PAD_VAL, PAD_VAL, PAD_VAL};
    u1 = u0;
  }

  float x[8] = {v0.x, v0.y, v0.z, v0.w, v1.x, v1.y, v1.z, v1.w};
  float y[8] = {u0.x, u0.y, u0.z, u0.w, u1.x, u1.y, u1.z, u1.w};
  const float kf = (float)(8 * lane);
#pragma unroll
  for (int t = 0; t < 8; ++t) x[t] -= kf + (float)t;
#pragma unroll
  for (int t = 0; t < 8; ++t) y[t] -= kf + (float)(t + 64);

  // ---- own suffix scan; lane aggregate m = suf[0] ----
  float suf[8];
  suf[7] = x[7];
#pragma unroll
  for (int t = 6; t >= 0; --t) suf[t] = fmaxf(suf[t + 1], x[t]);
  const float m = suf[0];

  // ---- next8 prefix scan (prefixes of lane L+8 / halo), aggregate m2 ----
  float pre2[8];
  pre2[0] = y[0];
#pragma unroll
  for (int t = 1; t < 8; ++t) pre2[t] = fmaxf(pre2[t - 1], y[t]);
  const float m2 = pre2[7];

  // ---- clamped doubling over lane aggregates (4 shuffles) ----
  const float w2 = fmaxf(m, __shfl_down(m, 1));
  const float w4 = fmaxf(w2, __shfl_down(w2, 2));
  const float a = __shfl_down(w4, 1);  // max(m[L+1..L+4]) clamped, valid L<=62
  const float b = __shfl_down(w4, 4);  // max(m[L+4..L+7]) clamped, valid L<=59
  const float midA = fmaxf(a, b);      // lanes <=55: m[L+1..L+7]
  const float tail = (lane <= 59) ? midA
                   : (lane <= 62) ? a
                                  : NEG_INF;  // lanes>=56: m[L+1..63]

  // ---- hi-lane virtual-lane scan: H = max(m2[56..L-1]) (4 shuffles).
  //      8-lane-group Kogge-Stone; groups elsewhere compute garbage,
  //      unused. ----
  float s = m2;
  {
    float q;
    q = __shfl_up(s, 1); if ((lane & 7) >= 1) s = fmaxf(s, q);
    q = __shfl_up(s, 2); if ((lane & 7) >= 2) s = fmaxf(s, q);
    q = __shfl_up(s, 4); if ((lane & 7) >= 4) s = fmaxf(s, q);
  }
  const float eH = __shfl_up(s, 1);
  const float H = ((lane & 7) >= 1) ? eH : NEG_INF;

  const bool hiLane = (lane >= 56);
  const float second = hiLane ? fmaxf(tail, H) : midA;

  // ---- combine + relu; third term = own pre2[t] for ALL lanes ----
  vfloat4 s0, s1;
#pragma unroll
  for (int t = 0; t < 8; ++t) {
    const float sufs = (t < 7) ? suf[t + 1] : NEG_INF;
    const float mw = fmaxf(fmaxf(sufs, second), pre2[t]);
    const float o = fmaxf(mw - x[t], 0.0f);
    if (t < 4) s0[t] = o; else s1[t - 4] = o;
  }

  // ---- nontemporal vector stores ----
  vfloat4* op4 = (vfloat4*)(outp + base);
  __builtin_nontemporal_store(s0, &op4[2 * lane]);
  __builtin_nontemporal_store(s1, &op4[2 * lane + 1]);
}

extern "C" void kernel_launch(void* const* d_in, const int* in_sizes, int n_in,
                              void* d_out, int out_size, void* d_ws, size_t ws_size,
                              hipStream_t stream) {
  const float* hf = (const float*)d_in[0];
  float* out = (float*)d_out;
  const int total = in_sizes[0];
  const int rows = total / N_COLS;                   // 1024
  const int waves = rows * (N_COLS / CHUNK);         // 8192 waves = exactly
  const int grid = waves / 4;                        // one co-resident generation
  slide_max_kernel<<<grid, 256, 0, stream>>>(hf, out);
}